// Round 6
// baseline (241.463 us; speedup 1.0000x reference)
//
#include <hip/hip_runtime.h>

// Laplacian stencil with wraparound (roll-based double gradient):
//   gx[h][w] = x[h-2][w] - 2*x[h-1][w] + x[h][w]   (mod 1024)
//   gy[h][w] = x[h][w-2] - 2*x[h][w-1] + x[h][w]   (mod 1024)
//   out = remove_nan(clip(gx + gy, -1, 1) * 0.5), inputs remove_nan(x, 1.0)
// x: (32, 1, 1024, 1024) f32.
//
// Structure: 1 block = 8-row full-width strip of one image. 256 threads,
// thread t owns float4-column t for all 8 rows. 10 row-loads + 8 west-pair
// loads per thread (all independent -> deep MLP). XCD-chunked block swizzle
// keeps each image (4 MB = one XCD's L2) on one XCD for halo-row reuse.
// Nontemporal stores keep the 134 MB write stream out of L2.

#define HH 1024
#define WW 1024
#define RPB 8       // output rows per block
#define NXCD 8

typedef float f32x4 __attribute__((ext_vector_type(4)));
typedef float f32x2 __attribute__((ext_vector_type(2)));

__device__ __forceinline__ float rn1(float v) {
    return (v != v) ? 1.0f : v;     // remove_nan(v, 1.0)
}

__global__ __launch_bounds__(256) void laplacian_kernel(
        const float* __restrict__ x, float* __restrict__ out) {
    // XCD-chunked swizzle: consecutive logical strips land on one XCD.
    // gridDim.x = 4096, divisible by 8 -> bijective.
    const int cpx = gridDim.x / NXCD;                       // 512
    const int wg  = (blockIdx.x % NXCD) * cpx + blockIdx.x / NXCD;

    const int strip = wg & 127;                             // 128 strips/image
    const int img_i = wg >> 7;                              // 0..31
    const int r0    = strip * RPB;
    const float* __restrict__ img  = x   + ((long)img_i << 20);
    float*       __restrict__ oimg = out + ((long)img_i << 20);

    const int c = threadIdx.x;                              // float4 column
    const int w = c << 2;

    // 10 row loads (rows r0-2 .. r0+7, wrap only affects strip 0)
    f32x4 rowv[RPB + 2];
    #pragma unroll
    for (int k = 0; k < RPB + 2; ++k) {
        const int r = (r0 + k - 2) & (HH - 1);
        rowv[k] = *(const f32x4*)(img + (r << 10) + w);
    }
    // west pairs (x[w-2], x[w-1]) per output row — contiguous even at wrap
    // (c==0 -> elements 1022,1023), 8B-aligned single load.
    f32x2 wp[RPB];
    const int wm2 = (w - 2) & (WW - 1);
    #pragma unroll
    for (int k = 0; k < RPB; ++k) {
        wp[k] = *(const f32x2*)(img + ((r0 + k) << 10) + wm2);
    }

    #pragma unroll
    for (int k = 0; k < RPB; ++k) {
        const f32x4 cur = rowv[k + 2];
        const f32x4 u1  = rowv[k + 1];
        const f32x4 u2  = rowv[k];
        const float cc[4] = { rn1(cur.x), rn1(cur.y), rn1(cur.z), rn1(cur.w) };
        const float a1[4] = { rn1(u1.x), rn1(u1.y), rn1(u1.z), rn1(u1.w) };
        const float a2[4] = { rn1(u2.x), rn1(u2.y), rn1(u2.z), rn1(u2.w) };
        const float west[6] = { rn1(wp[k].x), rn1(wp[k].y),
                                cc[0], cc[1], cc[2], cc[3] };
        f32x4 o;
        #pragma unroll
        for (int j = 0; j < 4; ++j) {
            const float gx = a2[j]   - 2.0f * a1[j]       + cc[j];
            const float gy = west[j] - 2.0f * west[j + 1] + cc[j];
            float g = gx + gy;
            g = fminf(fmaxf(g, -1.0f), 1.0f) * 0.5f;
            o[j] = (g != g) ? 0.0f : g;                    // remove_nan(g)
        }
        __builtin_nontemporal_store(o, (f32x4*)(oimg + ((r0 + k) << 10) + w));
    }
}

extern "C" void kernel_launch(void* const* d_in, const int* in_sizes, int n_in,
                              void* d_out, int out_size, void* d_ws, size_t ws_size,
                              hipStream_t stream) {
    const float* x = (const float*)d_in[0];
    float* out = (float*)d_out;
    const int blocks = 32 * (HH / RPB);         // 4096: 32 images x 128 strips
    laplacian_kernel<<<blocks, 256, 0, stream>>>(x, out);
}